// Round 7
// baseline (99.611 us; speedup 1.0000x reference)
//
#include <hip/hip_runtime.h>

// Moreau-tropical forward, round 7: register-tiled (4b x 4n per thread)
// two-pass over LDS tiles.
//
// z = x[b] + W[n] (D=1024); root of f(tau)=sum relu(z-tau)=lam in [M-lam, M],
// M = max(z); only z > M-lam contribute. Block = 8b x 8n pairs (64), 256 thr:
// thread = (quadrant pos in 2x2, d-group dg in 0..63) -> 4x4 pair tile over
// 16 d's. Each 8x16B LDS read feeds 64 pair-elements (2 B/pair-elem, 4x less
// than round 4). Pass 1 maxes -> 2-step shfl + stride-65 LDS tree. Pass 2
// re-reads with EXACT per-pair thresholds in registers (rare inserts). Solve:
// one wave, thread-per-pair register bisection (proven rounds 4-6, absmax 0).

#define D_DIM   1024
#define TB      8
#define TN      8
#define NPAIR   64
#define NTHR    256
#define SROW    1028          // LDS row stride: 16B-aligned, breaks pow2
#define CAPP    32
#define NB      16
#define NEG_INF (-3.0e38f)

__global__ void __launch_bounds__(NTHR, 2)
moreau_tropical(const float* __restrict__ x, const float* __restrict__ W,
                const float* __restrict__ lam_p, float* __restrict__ out,
                int B, int N) {
    __shared__ float xs[TB * SROW];          // 32.1 KB
    __shared__ float ws[TN * SROW];          // 32.1 KB
    __shared__ float cand[CAPP * NPAIR];     // 8 KB, cand[slot*64+p]
    __shared__ float pm[16 * 65];            // 4.06 KB, pm[gg*65+p] (65: bank spread)
    __shared__ float pmax[NPAIR];
    __shared__ int   pcnt[NPAIR];

    const int tid = threadIdx.x;
    const int dg  = tid & 63;                // d-group lane
    const int pos = tid >> 6;                // wave id -> quadrant
    const int tb  = pos >> 1;                // 0..1
    const int tn  = pos & 1;                 // 0..1
    const int b0  = blockIdx.y * TB;
    const int n0  = blockIdx.x * TN;
    const float lam = lam_p[0];

    // ---- stage tiles: coalesced global dwordx4 -> LDS b128 ----
#pragma unroll
    for (int i = 0; i < 8; ++i) {
        const int flat = tid + NTHR * i;     // 0..2047
        const int row  = flat >> 8;          // 0..7
        const int c4   = (flat & 255) << 2;  // 0..1020
        const int gb   = min(b0 + row, B - 1);
        const int gn   = min(n0 + row, N - 1);
        *(float4*)&xs[row * SROW + c4] = *(const float4*)(x + (size_t)gb * D_DIM + c4);
        *(float4*)&ws[row * SROW + c4] = *(const float4*)(W + (size_t)gn * D_DIM + c4);
    }
    if (tid < NPAIR) pcnt[tid] = 0;
    __syncthreads();

    // ---- pass 1: per-thread 4x4 running maxes over its 16 d's ----
    float m[16];
#pragma unroll
    for (int q = 0; q < 16; ++q) m[q] = NEG_INF;

#pragma unroll
    for (int k = 0; k < 4; ++k) {
        const int col = (k * 64 + dg) * 4;
        float4 xv[4], wv[4];
#pragma unroll
        for (int i = 0; i < 4; ++i) xv[i] = *(const float4*)&xs[(tb * 4 + i) * SROW + col];
#pragma unroll
        for (int j = 0; j < 4; ++j) wv[j] = *(const float4*)&ws[(tn * 4 + j) * SROW + col];
#pragma unroll
        for (int i = 0; i < 4; ++i)
#pragma unroll
            for (int j = 0; j < 4; ++j) {
                const float4 a = xv[i], c = wv[j];
                const float z0 = a.x + c.x, z1 = a.y + c.y;
                const float z2 = a.z + c.z, z3 = a.w + c.w;
                m[i * 4 + j] = fmaxf(m[i * 4 + j],
                                     fmaxf(fmaxf(z0, z1), fmaxf(z2, z3)));
            }
    }

    // ---- reduce over 64 dg: 2-step shfl (4 lanes) + LDS tree ----
#pragma unroll
    for (int q = 0; q < 16; ++q) {
        m[q] = fmaxf(m[q], __shfl_xor(m[q], 1, 64));
        m[q] = fmaxf(m[q], __shfl_xor(m[q], 2, 64));
    }
    if ((dg & 3) == 0) {
        const int gg = dg >> 2;              // 0..15
#pragma unroll
        for (int i = 0; i < 4; ++i)
#pragma unroll
            for (int j = 0; j < 4; ++j)
                pm[gg * 65 + (tb * 4 + i) * 8 + tn * 4 + j] = m[i * 4 + j];
    }
    __syncthreads();

    if (tid < NPAIR) {
        float v = pm[tid];
#pragma unroll
        for (int g = 1; g < 16; ++g) v = fmaxf(v, pm[g * 65 + tid]);
        pmax[tid] = v;
    }
    __syncthreads();

    // per-thread exact thresholds (broadcast reads)
    float thr[16];
    float tmin[4];
#pragma unroll
    for (int i = 0; i < 4; ++i) {
#pragma unroll
        for (int j = 0; j < 4; ++j)
            thr[i * 4 + j] = pmax[(tb * 4 + i) * 8 + tn * 4 + j] - lam;
        tmin[i] = fminf(fminf(thr[i * 4], thr[i * 4 + 1]),
                        fminf(thr[i * 4 + 2], thr[i * 4 + 3]));
    }

    // ---- pass 2: exact-threshold candidate extraction (rare inserts) ----
#pragma unroll
    for (int k = 0; k < 4; ++k) {
        const int col = (k * 64 + dg) * 4;
        float4 xv[4], wv[4];
#pragma unroll
        for (int i = 0; i < 4; ++i) xv[i] = *(const float4*)&xs[(tb * 4 + i) * SROW + col];
#pragma unroll
        for (int j = 0; j < 4; ++j) wv[j] = *(const float4*)&ws[(tn * 4 + j) * SROW + col];
#pragma unroll
        for (int i = 0; i < 4; ++i) {
            float g4[4];
#pragma unroll
            for (int j = 0; j < 4; ++j) {
                const float4 a = xv[i], c = wv[j];
                g4[j] = fmaxf(fmaxf(a.x + c.x, a.y + c.y),
                              fmaxf(a.z + c.z, a.w + c.w));
            }
            const float gi = fmaxf(fmaxf(g4[0], g4[1]), fmaxf(g4[2], g4[3]));
            if (gi > tmin[i]) {              // rare outer gate (~5%)
#pragma unroll
                for (int j = 0; j < 4; ++j) {
                    const float t = thr[i * 4 + j];
                    if (g4[j] > t) {
                        const float4 a = xv[i], c = wv[j];
                        const int pr = (tb * 4 + i) * 8 + tn * 4 + j;
                        const float z0 = a.x + c.x, z1 = a.y + c.y;
                        const float z2 = a.z + c.z, z3 = a.w + c.w;
                        if (z0 > t) { int s_ = atomicAdd(&pcnt[pr], 1); if (s_ < CAPP) cand[s_ * NPAIR + pr] = z0; }
                        if (z1 > t) { int s_ = atomicAdd(&pcnt[pr], 1); if (s_ < CAPP) cand[s_ * NPAIR + pr] = z1; }
                        if (z2 > t) { int s_ = atomicAdd(&pcnt[pr], 1); if (s_ < CAPP) cand[s_ * NPAIR + pr] = z2; }
                        if (z3 > t) { int s_ = atomicAdd(&pcnt[pr], 1); if (s_ < CAPP) cand[s_ * NPAIR + pr] = z3; }
                    }
                }
            }
        }
    }
    __syncthreads();

    // ---- solve: one wave, thread-per-pair (proven rounds 4-6) ----
    if (tid < NPAIR) {
        const int p  = tid;
        const int pb = p >> 3;
        const int pn = p & 7;
        const int K  = pcnt[p];
        const float M   = pmax[p];
        const float thr0 = M - lam;
        float tau, delta;

        if (K <= CAPP) {
            int Kw = K;
#pragma unroll
            for (int o = 1; o < 64; o <<= 1) Kw = max(Kw, __shfl_xor(Kw, o, 64));

            float lo = thr0, hi = M;
            for (int it = 0; it < NB; ++it) {
                const float mid = 0.5f * (lo + hi);
                float f = 0.0f;
                for (int j = 0; j < Kw; ++j) {
                    float v = cand[j * NPAIR + p];
                    v = (j < K) ? v : NEG_INF;
                    f += fmaxf(v - mid, 0.0f);
                }
                if (f > lam) lo = mid; else hi = mid;
            }
            tau = 0.5f * (lo + hi);
            float s2 = 0.0f;
            for (int j = 0; j < Kw; ++j) {
                float v = cand[j * NPAIR + p];
                v = (j < K) ? v : NEG_INF;
                const float t = fmaxf(v - tau, 0.0f);
                s2 += t * t;
            }
            delta = s2 / (2.0f * lam);
        } else {
            // overflow fallback (~never on this data): rows still in LDS
            const float* xr = &xs[pb * SROW];
            const float* wr = &ws[pn * SROW];
            float lo = thr0, hi = M;
            for (int it = 0; it < NB; ++it) {
                const float mid = 0.5f * (lo + hi);
                float f = 0.0f;
                for (int d = 0; d < D_DIM; ++d)
                    f += fmaxf(xr[d] + wr[d] - mid, 0.0f);
                if (f > lam) lo = mid; else hi = mid;
            }
            tau = 0.5f * (lo + hi);
            float s2 = 0.0f;
            for (int d = 0; d < D_DIM; ++d) {
                const float t = fmaxf(xr[d] + wr[d] - tau, 0.0f);
                s2 += t * t;
            }
            delta = s2 / (2.0f * lam);
        }

        const int ob = min(b0 + pb, B - 1);
        const int on = min(n0 + pn, N - 1);
        out[(size_t)ob * N + on] = tau + delta;
    }
}

extern "C" void kernel_launch(void* const* d_in, const int* in_sizes, int n_in,
                              void* d_out, int out_size, void* d_ws, size_t ws_size,
                              hipStream_t stream) {
    const float* x    = (const float*)d_in[0];
    const float* W    = (const float*)d_in[1];
    const float* lamp = (const float*)d_in[2];
    float* out        = (float*)d_out;

    const int B = in_sizes[0] / D_DIM;
    const int N = in_sizes[1] / D_DIM;

    dim3 grid((N + TN - 1) / TN, (B + TB - 1) / TB);
    moreau_tropical<<<grid, NTHR, 0, stream>>>(x, W, lamp, out, B, N);
}